// Round 2
// baseline (185.546 us; speedup 1.0000x reference)
//
#include <hip/hip_runtime.h>

typedef _Float16 half_t;
typedef _Float16 half2_t __attribute__((ext_vector_type(2)));
typedef _Float16 half4_t __attribute__((ext_vector_type(4)));
typedef _Float16 half8 __attribute__((ext_vector_type(8)));
typedef float f32x4 __attribute__((ext_vector_type(4)));

__device__ __forceinline__ void gload_lds16(const void* g, void* l) {
    __builtin_amdgcn_global_load_lds(
        (const __attribute__((address_space(1))) void*)g,
        (__attribute__((address_space(3))) void*)l, 16, 0, 0);
}

// ---------------- cast fp32 -> fp16 (vectorized, grid-stride) ----------------
__global__ __launch_bounds__(256) void cast_f32_f16(const float* __restrict__ s,
                                                    half_t* __restrict__ d, int n) {
    const int stride = gridDim.x * blockDim.x;
    for (int i = blockIdx.x * blockDim.x + threadIdx.x; i * 4 < n; i += stride) {
        const float4 v = *(const float4*)(s + (long)i * 4);
        half4_t h = {(half_t)v.x, (half_t)v.y, (half_t)v.z, (half_t)v.w};
        *(half4_t*)(d + (long)i * 4) = h;
    }
}

__global__ __launch_bounds__(256) void concat_bias(const float* __restrict__ a,
                                                   const float* __restrict__ b,
                                                   const float* __restrict__ c,
                                                   float* __restrict__ o) {
    int i = blockIdx.x * blockDim.x + threadIdx.x;
    if (i < 768) o[i] = a[i];
    else if (i < 1536) o[i] = b[i - 768];
    else if (i < 2304) o[i] = c[i - 1536];
}

// ---------------- GEMM: C[M,N] = A[M,K] * W[N,K]^T + bias[N] ----------------
// m97 structure: 128x128 tile, BK=32, 4 waves (2x2), 16x16x32 fp16 MFMA,
// global_load_lds width-16 staging, single LDS buffer, 2 barriers / K-step.
template <typename OutT>
__global__ __launch_bounds__(256) void gemm_bt(const half_t* __restrict__ A,
                                               const half_t* __restrict__ W,
                                               const float* __restrict__ bias,
                                               OutT* __restrict__ C,
                                               int M, int N, int K) {
    alignas(16) __shared__ half_t Ah[128 * 32];
    alignas(16) __shared__ half_t Wh[128 * 32];
    const int t = threadIdx.x;
    const int l = t & 63, w = t >> 6;
    const int m0 = blockIdx.x * 128, n0 = blockIdx.y * 128;
    const int wr = w >> 1, wc = w & 1;

    f32x4 acc[4][4] = {};

    // staging: per call each wave covers 16 rows (lane l -> row l/4, chunk l%4)
    const int srow = w * 16 + (l >> 2);
    const int scol = (l & 3) * 8;
    const half_t* Ag = A + (long)(m0 + srow) * K + scol;
    const half_t* Wg = W + (long)(n0 + srow) * K + scol;
    half_t* lA0 = &Ah[(w * 16) * 32];
    half_t* lA1 = &Ah[(w * 16 + 64) * 32];
    half_t* lW0 = &Wh[(w * 16) * 32];
    half_t* lW1 = &Wh[(w * 16 + 64) * 32];

    for (int k0 = 0; k0 < K; k0 += 32) {
        gload_lds16(Ag + k0, lA0);
        gload_lds16(Ag + (long)64 * K + k0, lA1);
        gload_lds16(Wg + k0, lW0);
        gload_lds16(Wg + (long)64 * K + k0, lW1);
        __syncthreads();

        half8 af[4], bf[4];
        const int ak = (l >> 4) * 8;
#pragma unroll
        for (int m = 0; m < 4; ++m)
            af[m] = *(const half8*)&Ah[(wr * 64 + m * 16 + (l & 15)) * 32 + ak];
#pragma unroll
        for (int n = 0; n < 4; ++n)
            bf[n] = *(const half8*)&Wh[(wc * 64 + n * 16 + (l & 15)) * 32 + ak];
#pragma unroll
        for (int m = 0; m < 4; ++m)
#pragma unroll
            for (int n = 0; n < 4; ++n)
                acc[m][n] = __builtin_amdgcn_mfma_f32_16x16x32_f16(af[m], bf[n], acc[m][n], 0, 0, 0);
        __syncthreads();
    }

    // epilogue: C/D layout col = lane&15, row = (lane>>4)*4 + r
#pragma unroll
    for (int m = 0; m < 4; ++m) {
        const int row = m0 + wr * 64 + m * 16 + (l >> 4) * 4;
#pragma unroll
        for (int n = 0; n < 4; ++n) {
            const int col = n0 + wc * 64 + n * 16 + (l & 15);
            const float bb = bias ? bias[col] : 0.f;
#pragma unroll
            for (int r = 0; r < 4; ++r) {
                float v = acc[m][n][r] + bb;
                C[(long)(row + r) * N + col] = (OutT)v;
            }
        }
    }
}

// ---------------- flash attention ----------------
// grid: (16 qtiles, 96 heads). block: 256 thr = 4 waves, each wave 16 Q-rows.
// QKV layout: [B*1024, 2304] fp16, Q at col h*64, K at 768+h*64, V at 1536+h*64.
__global__ __launch_bounds__(256) void attn_kernel(const half_t* __restrict__ QKV,
                                                   const float* __restrict__ head_mask,
                                                   half_t* __restrict__ Y) {
    alignas(16) __shared__ half_t Kl[64 * 64];      // K-tile, chunk-swizzled rows
    alignas(16) __shared__ half_t Vt[64 * 72];      // V transposed [d][kv], pad 72
    alignas(16) __shared__ half_t Pl[4][16 * 72];   // per-wave P, pad 72

    const int t = threadIdx.x, l = t & 63, w = t >> 6;
    const int qt = blockIdx.x, bh = blockIdx.y;
    const int b = bh / 12, h = bh % 12;
    const long base = (long)b * 1024 * 2304;
    const half_t* Qp = QKV + base + h * 64;
    const half_t* Kp = QKV + base + 768 + h * 64;
    const half_t* Vp = QKV + base + 1536 + h * 64;

    // Q fragments: row = l&15 within wave's 16 rows, k = kc*32 + (l>>4)*8
    half8 qf[2];
    {
        const long qrow = qt * 64 + w * 16 + (l & 15);
#pragma unroll
        for (int kc = 0; kc < 2; ++kc)
            qf[kc] = *(const half8*)(Qp + qrow * 2304 + kc * 32 + (l >> 4) * 8);
    }

    f32x4 o[4] = {};
    float mrow[4], lrow[4];
#pragma unroll
    for (int r = 0; r < 4; ++r) { mrow[r] = -1e30f; lrow[r] = 0.f; }

    for (int kv = 0; kv < 16; ++kv) {
        // ---- stage K with pre-swizzled global source, linear LDS dest ----
#pragma unroll
        for (int c = 0; c < 2; ++c) {
            const int row = c * 32 + w * 8 + (l >> 3);
            const int chunk = (l & 7) ^ (row & 7);
            gload_lds16(Kp + (long)(kv * 64 + row) * 2304 + chunk * 8,
                        &Kl[(c * 32 + w * 8) * 64]);
        }
        // ---- stage V transposed: thread covers 2 kv-rows x 8 d-cols ----
        {
            const int r2 = (t & 31) * 2;
            const int c0 = (t >> 5) * 8;
            const half8 v0 = *(const half8*)(Vp + (long)(kv * 64 + r2) * 2304 + c0);
            const half8 v1 = *(const half8*)(Vp + (long)(kv * 64 + r2 + 1) * 2304 + c0);
#pragma unroll
            for (int j = 0; j < 8; ++j) {
                half2_t pr2 = {v0[j], v1[j]};
                *(half2_t*)&Vt[(c0 + j) * 72 + r2] = pr2;
            }
        }
        __syncthreads();

        // ---- S = Q K^T (per wave: 16 q-rows x 64 kv) ----
        f32x4 s[4] = {};
#pragma unroll
        for (int kc = 0; kc < 2; ++kc)
#pragma unroll
            for (int nt = 0; nt < 4; ++nt) {
                const int row = nt * 16 + (l & 15);
                const int sl = (kc * 4 + (l >> 4)) ^ (row & 7);
                half8 kb = *(const half8*)&Kl[row * 64 + sl * 8];
                s[nt] = __builtin_amdgcn_mfma_f32_16x16x32_f16(qf[kc], kb, s[nt], 0, 0, 0);
            }
#pragma unroll
        for (int nt = 0; nt < 4; ++nt) s[nt] *= 0.125f;

        // ---- online softmax (rows = (l>>4)*4 + r, reduce across 16-lane group) ----
        float pv[4][4];
#pragma unroll
        for (int r = 0; r < 4; ++r) {
            float mx = fmaxf(fmaxf(s[0][r], s[1][r]), fmaxf(s[2][r], s[3][r]));
#pragma unroll
            for (int x = 8; x > 0; x >>= 1) mx = fmaxf(mx, __shfl_xor(mx, x, 64));
            const float mnew = fmaxf(mrow[r], mx);
            const float alpha = __expf(mrow[r] - mnew);
            mrow[r] = mnew;
            float rs = 0.f;
#pragma unroll
            for (int nt = 0; nt < 4; ++nt) {
                float p = __expf(s[nt][r] - mnew);
                pv[nt][r] = p;
                rs += p;
            }
#pragma unroll
            for (int x = 8; x > 0; x >>= 1) rs += __shfl_xor(rs, x, 64);
            lrow[r] = lrow[r] * alpha + rs;
#pragma unroll
            for (int dt = 0; dt < 4; ++dt) o[dt][r] *= alpha;
        }

        // ---- repack P via per-wave LDS ----
#pragma unroll
        for (int nt = 0; nt < 4; ++nt)
#pragma unroll
            for (int r = 0; r < 4; ++r)
                Pl[w][((l >> 4) * 4 + r) * 72 + nt * 16 + (l & 15)] = (half_t)pv[nt][r];

        // ---- O += P V ----
#pragma unroll
        for (int kc2 = 0; kc2 < 2; ++kc2) {
            half8 pa = *(const half8*)&Pl[w][(l & 15) * 72 + kc2 * 32 + (l >> 4) * 8];
#pragma unroll
            for (int dt = 0; dt < 4; ++dt) {
                half8 vb = *(const half8*)&Vt[(dt * 16 + (l & 15)) * 72 + kc2 * 32 + (l >> 4) * 8];
                o[dt] = __builtin_amdgcn_mfma_f32_16x16x32_f16(pa, vb, o[dt], 0, 0, 0);
            }
        }
        __syncthreads();
    }

    // ---- epilogue: normalize, mask^2, write y fp16 [8192,768] ----
    const float hm = head_mask[b * 12 + h];
    const float m2 = hm * hm;
#pragma unroll
    for (int dt = 0; dt < 4; ++dt)
#pragma unroll
        for (int r = 0; r < 4; ++r) {
            const int qrow = qt * 64 + w * 16 + (l >> 4) * 4 + r;
            const float val = o[dt][r] / lrow[r] * m2;
            Y[(long)(b * 1024 + qrow) * 768 + h * 64 + dt * 16 + (l & 15)] = (half_t)val;
        }
}

// ---------------- launch ----------------
extern "C" void kernel_launch(void* const* d_in, const int* in_sizes, int n_in,
                              void* d_out, int out_size, void* d_ws, size_t ws_size,
                              hipStream_t stream) {
    const float* x   = (const float*)d_in[0];
    const float* hm  = (const float*)d_in[1];
    const float* q_w = (const float*)d_in[2];
    const float* q_b = (const float*)d_in[3];
    const float* k_w = (const float*)d_in[4];
    const float* k_b = (const float*)d_in[5];
    const float* v_w = (const float*)d_in[6];
    const float* v_b = (const float*)d_in[7];
    const float* p_w = (const float*)d_in[8];
    const float* p_b = (const float*)d_in[9];
    float* out = (float*)d_out;

    char* ws = (char*)d_ws;
    half_t* xh  = (half_t*)(ws);                    // 8192*768*2   = 12582912
    half_t* wc  = (half_t*)(ws + 12582912);         // 2304*768*2   = 3538944
    half_t* pwh = (half_t*)(ws + 16121856);         // 768*768*2    = 1179648
    float*  bc  = (float*)(ws + 17301504);          // 2304*4       = 9216
    half_t* qkv = (half_t*)(ws + 17310720);         // 8192*2304*2  = 37748736
    half_t* y   = (half_t*)(ws + 55059456);         // 8192*768*2   = 12582912

    cast_f32_f16<<<2048, 256, 0, stream>>>(x, xh, 8192 * 768);
    cast_f32_f16<<<576, 256, 0, stream>>>(q_w, wc, 768 * 768);
    cast_f32_f16<<<576, 256, 0, stream>>>(k_w, wc + 768 * 768, 768 * 768);
    cast_f32_f16<<<576, 256, 0, stream>>>(v_w, wc + 2 * 768 * 768, 768 * 768);
    cast_f32_f16<<<576, 256, 0, stream>>>(p_w, pwh, 768 * 768);
    concat_bias<<<9, 256, 0, stream>>>(q_b, k_b, v_b, bc);

    gemm_bt<half_t><<<dim3(64, 18), 256, 0, stream>>>(xh, wc, bc, qkv, 8192, 2304, 768);
    attn_kernel<<<dim3(16, 96), 256, 0, stream>>>(qkv, hm, y);
    gemm_bt<float><<<dim3(64, 6), 256, 0, stream>>>(y, pwh, p_b, out, 8192, 768, 768);
}